// Round 1
// baseline (3173.114 us; speedup 1.0000x reference)
//
#include <hip/hip_runtime.h>
#include <hip/hip_bf16.h>

// Problem constants (S=2048, B=2, H=4096, M=16384)
#define S_ 2048
#define B_ 2
#define H_ 4096
#define M_ 16384
#define R_ (S_ * B_)  // 4096 rows

typedef unsigned short u16;
typedef __attribute__((ext_vector_type(8))) short short8;
typedef __attribute__((ext_vector_type(4))) float f32x4;

__device__ __forceinline__ u16 f2bf(float f) {
  union { float f; unsigned u; } a; a.f = f;
  unsigned r = (a.u + 0x7FFFu + ((a.u >> 16) & 1u)) >> 16;  // RNE
  return (u16)r;
}

__device__ __forceinline__ void gload16(const u16* gp, u16* lp) {
  // HW writes lane l's 16B at lp + l*16 (wave-uniform LDS base).
  __builtin_amdgcn_global_load_lds(
      (const __attribute__((address_space(1))) void*)gp,
      (__attribute__((address_space(3))) void*)lp, 16, 0, 0);
}

// ---------------- LayerNorm: f32 in -> f32 out (output #1) + bf16 copy ----------------
__global__ __launch_bounds__(256) void ln_kernel(
    const float* __restrict__ x, const float* __restrict__ scale,
    const float* __restrict__ bias, float* __restrict__ ln_f32,
    u16* __restrict__ ln_bf16) {
  const int row = blockIdx.x;
  const float* xr = x + (size_t)row * H_;
  const int t = threadIdx.x;
  float4 v[4];
  float s = 0.f, s2 = 0.f;
#pragma unroll
  for (int i = 0; i < 4; i++) {
    v[i] = ((const float4*)xr)[t + 256 * i];
    s  += v[i].x + v[i].y + v[i].z + v[i].w;
    s2 += v[i].x * v[i].x + v[i].y * v[i].y + v[i].z * v[i].z + v[i].w * v[i].w;
  }
#pragma unroll
  for (int o = 32; o >= 1; o >>= 1) {
    s  += __shfl_xor(s, o);
    s2 += __shfl_xor(s2, o);
  }
  __shared__ float red[8];
  const int w = t >> 6;
  if ((t & 63) == 0) { red[w] = s; red[4 + w] = s2; }
  __syncthreads();
  const float S1 = red[0] + red[1] + red[2] + red[3];
  const float S2 = red[4] + red[5] + red[6] + red[7];
  const float mu = S1 * (1.f / H_);
  const float var = S2 * (1.f / H_) - mu * mu;
  const float rs = rsqrtf(var + 1e-6f);
  float* of = ln_f32 + (size_t)row * H_;
  u16* ob = ln_bf16 + (size_t)row * H_;
#pragma unroll
  for (int i = 0; i < 4; i++) {
    float4 g  = ((const float4*)scale)[t + 256 * i];
    float4 bb = ((const float4*)bias)[t + 256 * i];
    float4 y;
    y.x = (v[i].x - mu) * rs * g.x + bb.x;
    y.y = (v[i].y - mu) * rs * g.y + bb.y;
    y.z = (v[i].z - mu) * rs * g.z + bb.z;
    y.w = (v[i].w - mu) * rs * g.w + bb.w;
    ((float4*)of)[t + 256 * i] = y;
    ushort4 ov;
    ov.x = f2bf(y.x); ov.y = f2bf(y.y); ov.z = f2bf(y.z); ov.w = f2bf(y.w);
    ((ushort4*)ob)[t + 256 * i] = ov;
  }
}

// ---------------- Transpose + convert: f32 [K][N] -> bf16 [N][K] ----------------
__global__ __launch_bounds__(256) void convT_kernel(
    const float* __restrict__ in, u16* __restrict__ out, int K, int N) {
  __shared__ float lds[32][33];
  const int n0 = blockIdx.x * 32;
  const int k0 = blockIdx.y * 32;
  const int t = threadIdx.x;
  const int r = t >> 5, c = t & 31;
#pragma unroll
  for (int rr = 0; rr < 4; rr++)
    lds[r + 8 * rr][c] = in[(size_t)(k0 + r + 8 * rr) * N + n0 + c];
  __syncthreads();
  const int nl = t >> 3, k4 = (t & 7) * 4;
  ushort4 o;
  o.x = f2bf(lds[k4 + 0][nl]);
  o.y = f2bf(lds[k4 + 1][nl]);
  o.z = f2bf(lds[k4 + 2][nl]);
  o.w = f2bf(lds[k4 + 3][nl]);
  *(ushort4*)&out[(size_t)(n0 + nl) * K + k0 + k4] = o;
}

// ---------------- GEMM1: C = lnb[4096][4096] . k1T^T, dual-branch + gated GELU -> z bf16 ----------------
// Block: 128 rows x 64 cols per branch (branch0 = k1T rows [c0,c0+64), branch1 = +M_).
__global__ __launch_bounds__(256, 2) void gemm1_kernel(
    const u16* __restrict__ A,   // [R_][4096] bf16 ln
    const u16* __restrict__ Bt,  // [2*M_][4096] bf16 k1 transposed
    u16* __restrict__ Z) {       // [R_][M_] bf16
  __shared__ u16 As[128 * 64];
  __shared__ u16 B0s[64 * 64];
  __shared__ u16 B1s[64 * 64];
  const int K = H_;
  const int t = threadIdx.x;
  const int w = t >> 6, lane = t & 63;
  const int lr = lane & 15, lk = (lane >> 4) * 8;
  const int wr = (w >> 1) * 64, wc = (w & 1) * 32;
  const int r0 = blockIdx.y * 128;
  const int c0 = blockIdx.x * 64;
  const int lrow = lane >> 3;         // 0..7 row within staging chunk
  const int lcol8 = (lane & 7) * 8;   // k offset within 64
  f32x4 acc0[4][2], acc1[4][2];
#pragma unroll
  for (int i = 0; i < 4; i++)
#pragma unroll
    for (int j = 0; j < 2; j++) { acc0[i][j] = (f32x4){0,0,0,0}; acc1[i][j] = (f32x4){0,0,0,0}; }

  for (int kt = 0; kt < K; kt += 64) {
#pragma unroll
    for (int i = 0; i < 4; i++) {
      int ch = w + 4 * i;  // 16 A-chunks of 1KB
      gload16(&A[(size_t)(r0 + ch * 8 + lrow) * K + kt + lcol8], &As[ch * 512]);
    }
#pragma unroll
    for (int i = 0; i < 2; i++) {
      int ch = w + 4 * i;  // 8 chunks each
      gload16(&Bt[(size_t)(c0 + ch * 8 + lrow) * K + kt + lcol8], &B0s[ch * 512]);
      gload16(&Bt[(size_t)(M_ + c0 + ch * 8 + lrow) * K + kt + lcol8], &B1s[ch * 512]);
    }
    __syncthreads();
#pragma unroll
    for (int ks = 0; ks < 2; ks++) {
      short8 a[4], b0[2], b1[2];
#pragma unroll
      for (int mi = 0; mi < 4; mi++)
        a[mi] = *(const short8*)&As[(wr + mi * 16 + lr) * 64 + ks * 32 + lk];
#pragma unroll
      for (int ni = 0; ni < 2; ni++) {
        b0[ni] = *(const short8*)&B0s[(wc + ni * 16 + lr) * 64 + ks * 32 + lk];
        b1[ni] = *(const short8*)&B1s[(wc + ni * 16 + lr) * 64 + ks * 32 + lk];
      }
#pragma unroll
      for (int mi = 0; mi < 4; mi++)
#pragma unroll
        for (int ni = 0; ni < 2; ni++) {
          acc0[mi][ni] = __builtin_amdgcn_mfma_f32_16x16x32_bf16(a[mi], b0[ni], acc0[mi][ni], 0, 0, 0);
          acc1[mi][ni] = __builtin_amdgcn_mfma_f32_16x16x32_bf16(a[mi], b1[ni], acc1[mi][ni], 0, 0, 0);
        }
    }
    __syncthreads();
  }
  // Epilogue: z = gelu_tanh(h0) * h1, write bf16
  const int orow = (lane >> 4) * 4;
#pragma unroll
  for (int mi = 0; mi < 4; mi++)
#pragma unroll
    for (int ni = 0; ni < 2; ni++)
#pragma unroll
      for (int rg = 0; rg < 4; rg++) {
        float h0 = acc0[mi][ni][rg];
        float h1 = acc1[mi][ni][rg];
        float u = 0.7978845608028654f * (h0 + 0.044715f * h0 * h0 * h0);
        float e = __expf(2.f * u);
        float th = 1.f - 2.f / (e + 1.f);  // tanh(u), safe at +inf
        float zv = 0.5f * h0 * (1.f + th) * h1;
        int rr = r0 + wr + mi * 16 + orow + rg;
        int cc = c0 + wc + ni * 16 + lr;
        Z[(size_t)rr * M_ + cc] = f2bf(zv);
      }
}

// ---------------- GEMM2: out = z[4096][16384] . k2T^T -> f32 [4096][4096] ----------------
__global__ __launch_bounds__(256, 2) void gemm2_kernel(
    const u16* __restrict__ A,   // z bf16 [R_][M_]
    const u16* __restrict__ Bt,  // k2T bf16 [H_][M_]
    float* __restrict__ C) {     // [R_][H_]
  __shared__ u16 As[128 * 64];
  __shared__ u16 Bs[128 * 64];
  const int K = M_;
  const int t = threadIdx.x;
  const int w = t >> 6, lane = t & 63;
  const int lr = lane & 15, lk = (lane >> 4) * 8;
  const int wr = (w >> 1) * 64, wc = (w & 1) * 64;
  const int r0 = blockIdx.y * 128;
  const int c0 = blockIdx.x * 128;
  const int lrow = lane >> 3;
  const int lcol8 = (lane & 7) * 8;
  f32x4 acc[4][4];
#pragma unroll
  for (int i = 0; i < 4; i++)
#pragma unroll
    for (int j = 0; j < 4; j++) acc[i][j] = (f32x4){0,0,0,0};

  for (int kt = 0; kt < K; kt += 64) {
#pragma unroll
    for (int i = 0; i < 4; i++) {
      int ch = w + 4 * i;
      gload16(&A[(size_t)(r0 + ch * 8 + lrow) * K + kt + lcol8], &As[ch * 512]);
      gload16(&Bt[(size_t)(c0 + ch * 8 + lrow) * K + kt + lcol8], &Bs[ch * 512]);
    }
    __syncthreads();
#pragma unroll
    for (int ks = 0; ks < 2; ks++) {
      short8 a[4], b[4];
#pragma unroll
      for (int mi = 0; mi < 4; mi++)
        a[mi] = *(const short8*)&As[(wr + mi * 16 + lr) * 64 + ks * 32 + lk];
#pragma unroll
      for (int ni = 0; ni < 4; ni++)
        b[ni] = *(const short8*)&Bs[(wc + ni * 16 + lr) * 64 + ks * 32 + lk];
#pragma unroll
      for (int mi = 0; mi < 4; mi++)
#pragma unroll
        for (int ni = 0; ni < 4; ni++)
          acc[mi][ni] = __builtin_amdgcn_mfma_f32_16x16x32_bf16(a[mi], b[ni], acc[mi][ni], 0, 0, 0);
    }
    __syncthreads();
  }
  const int orow = (lane >> 4) * 4;
#pragma unroll
  for (int mi = 0; mi < 4; mi++)
#pragma unroll
    for (int ni = 0; ni < 4; ni++)
#pragma unroll
      for (int rg = 0; rg < 4; rg++) {
        int rr = r0 + wr + mi * 16 + orow + rg;
        int cc = c0 + wc + ni * 16 + lr;
        C[(size_t)rr * H_ + cc] = acc[mi][ni][rg];
      }
}

extern "C" void kernel_launch(void* const* d_in, const int* in_sizes, int n_in,
                              void* d_out, int out_size, void* d_ws, size_t ws_size,
                              hipStream_t stream) {
  (void)in_sizes; (void)n_in; (void)out_size; (void)ws_size;
  const float* x     = (const float*)d_in[0];
  const float* scale = (const float*)d_in[1];
  const float* bias  = (const float*)d_in[2];
  const float* k1    = (const float*)d_in[3];  // [H_][2*M_] f32
  const float* k2    = (const float*)d_in[4];  // [M_][H_]  f32

  float* out   = (float*)d_out;                       // output 0: [R_][H_]
  float* lnout = (float*)d_out + (size_t)R_ * H_;     // output 1: [R_][H_]

  // Workspace layout (bytes): lnb 32M | k1T 256M | k2T 128M | z 128M  (total 544MB)
  char* ws = (char*)d_ws;
  u16* lnb = (u16*)ws;
  u16* k1T = (u16*)(ws + (size_t)33554432);
  u16* k2T = (u16*)(ws + (size_t)33554432 + 268435456);
  u16* z   = (u16*)(ws + (size_t)33554432 + 268435456 + 134217728);

  ln_kernel<<<R_, 256, 0, stream>>>(x, scale, bias, lnout, lnb);
  convT_kernel<<<dim3(2 * M_ / 32, H_ / 32), 256, 0, stream>>>(k1, k1T, H_, 2 * M_);
  convT_kernel<<<dim3(H_ / 32, M_ / 32), 256, 0, stream>>>(k2, k2T, M_, H_);
  gemm1_kernel<<<dim3(M_ / 64, R_ / 128), 256, 0, stream>>>(lnb, k1T, z);
  gemm2_kernel<<<dim3(H_ / 128, R_ / 128), 256, 0, stream>>>(z, k2T, out);
}